// Round 1
// baseline (1129.190 us; speedup 1.0000x reference)
//
#include <hip/hip_runtime.h>
#include <cstdint>
#include <cstddef>

#define B_ 64
#define N_ 16384
#define C_ 10
#define D_ 8
#define E_ 16
#define NT_ 32                 // n's per block
#define NCHUNK_ (NT_ / 16)
#define NBLK_ (N_ / NT_)       // 512 blocks
#define SVOL_ (B_ * C_ * E_)   // 10240 floats

// ---------------------------------------------------------------------------
// accum kernel: one routing pass's s accumulation.
// ITER==0: uniform coupling c=0.1 (softmax of zeros).
// ITER==1: logits = u_hat . v_acc   (v_acc = v0, or v0+v1 for the last pass)
// Each block: n-slice of NT_ n's, all 64 batches. W slice lives in registers
// (80 VGPR/thread), so W streams from HBM exactly once per pass.
// s partials accumulate in LDS (lds_s[64][160]) via shfl pre-reduce + LDS
// atomics, then flush with global atomics into ncopy striped accumulators.
// ---------------------------------------------------------------------------
template <int ITER>
__global__ __launch_bounds__(256) void accum_kernel(
    const float* __restrict__ x,     // [B][N][D]
    const float* __restrict__ W,     // [N][C][D][E]
    const float* __restrict__ vacc,  // [B][C][E]
    float* __restrict__ scopy,       // [ncopy][B][C][E]
    int ncopy)
{
  __shared__ float lds_s[SVOL_];        // 40 KB
  __shared__ float xtile[B_ * 16 * D_]; // 32 KB
  const int tid = threadIdx.x;
  const int e = tid & 15;   // capsule-dim lane
  const int g = tid >> 4;   // n-subindex within chunk (0..15)
  const int n0 = blockIdx.x * NT_;

  for (int i = tid; i < SVOL_; i += 256) lds_s[i] = 0.f;

  for (int ch = 0; ch < NCHUNK_; ++ch) {
    __syncthreads();  // previous chunk's xtile readers done; lds_s init done
    // stage x[b][n0+ch*16 .. +15][0..7] for all b (coalesced)
    const size_t xbase = (size_t)(n0 + ch * 16) * D_;
    for (int i = tid; i < B_ * 16 * D_; i += 256) {
      int b = i >> 7, r = i & 127;
      xtile[i] = x[(size_t)b * (N_ * D_) + xbase + r];
    }
    // W slice for this thread's n into registers
    const int n = n0 + ch * 16 + g;
    float w[C_][D_];
    const float* Wp = W + (size_t)n * (C_ * D_ * E_) + e;
#pragma unroll
    for (int c = 0; c < C_; ++c)
#pragma unroll
      for (int d = 0; d < D_; ++d)
        w[c][d] = Wp[(c * D_ + d) * E_];
    __syncthreads();

    for (int b = 0; b < B_; ++b) {
      float xd[D_];
#pragma unroll
      for (int d = 0; d < D_; ++d) xd[d] = xtile[b * 128 + g * 8 + d];
      // u_hat[c][e] for this (b, n)
      float u[C_];
#pragma unroll
      for (int c = 0; c < C_; ++c) {
        float acc = xd[0] * w[c][0];
#pragma unroll
        for (int d = 1; d < D_; ++d) acc = fmaf(xd[d], w[c][d], acc);
        u[c] = acc;
      }
      float cw[C_];
      if (ITER == 0) {
#pragma unroll
        for (int c = 0; c < C_; ++c) cw[c] = 0.1f;
      } else {
        // logits a[c] = sum_e u[c][e] * vacc[b][c][e]  (reduce over 16 e-lanes)
        float a[C_];
#pragma unroll
        for (int c = 0; c < C_; ++c) {
          float t = u[c] * vacc[(b * C_ + c) * E_ + e];
          t += __shfl_xor(t, 1);
          t += __shfl_xor(t, 2);
          t += __shfl_xor(t, 4);
          t += __shfl_xor(t, 8);
          a[c] = t;
        }
        float m = a[0];
#pragma unroll
        for (int c = 1; c < C_; ++c) m = fmaxf(m, a[c]);
        float ssum = 0.f;
#pragma unroll
        for (int c = 0; c < C_; ++c) { a[c] = __expf(a[c] - m); ssum += a[c]; }
        float inv = 1.0f / ssum;
#pragma unroll
        for (int c = 0; c < C_; ++c) cw[c] = a[c] * inv;
      }
      // s[b][c][e] += cw[c] * u[c][e]; pre-reduce the wave's 4 n's (xor 16,32)
#pragma unroll
      for (int c = 0; c < C_; ++c) {
        float p = cw[c] * u[c];
        p += __shfl_xor(p, 16);
        p += __shfl_xor(p, 32);
        if ((tid & 48) == 0)
          atomicAdd(&lds_s[b * (C_ * E_) + c * E_ + e], p);  // ds_add_f32
      }
    }
  }
  __syncthreads();
  float* sc = scopy + (size_t)(blockIdx.x & (ncopy - 1)) * SVOL_;
  for (int i = tid; i < SVOL_; i += 256) atomicAdd(&sc[i], lds_s[i]);
}

// ---------------------------------------------------------------------------
// squash kernel: reduce the striped s copies, apply squash.
// MODE 0: vacc = v (first pass)   MODE 1: vacc += v   MODE 2: out = v (final)
// 16 consecutive lanes = one (b,c) capsule.
// ---------------------------------------------------------------------------
template <int MODE>
__global__ __launch_bounds__(256) void squash_kernel(
    const float* __restrict__ scopy, int ncopy,
    float* __restrict__ vacc, float* __restrict__ out)
{
  int tid = blockIdx.x * 256 + threadIdx.x;  // 0..10239 exactly
  float sv = 0.f;
  for (int k = 0; k < ncopy; ++k) sv += scopy[(size_t)k * SVOL_ + tid];
  float sq = sv * sv;
  sq += __shfl_xor(sq, 1);
  sq += __shfl_xor(sq, 2);
  sq += __shfl_xor(sq, 4);
  sq += __shfl_xor(sq, 8);
  float scale = sq / (1.f + sq) * rsqrtf(sq + 1e-7f);
  float v = scale * sv;
  if (MODE == 0)      vacc[tid] = v;
  else if (MODE == 1) vacc[tid] += v;
  else                out[tid] = v;
}

extern "C" void kernel_launch(void* const* d_in, const int* in_sizes, int n_in,
                              void* d_out, int out_size, void* d_ws, size_t ws_size,
                              hipStream_t stream)
{
  const float* x = (const float*)d_in[0];  // [64][16384][8]
  const float* W = (const float*)d_in[1];  // [16384][10][8][16]
  float* out = (float*)d_out;              // [64][10][16]

  // ws: [ncopy striped s accumulators][v_acc]
  int ncopy = 16;
  while (ncopy > 1 && (size_t)(ncopy + 1) * SVOL_ * sizeof(float) > ws_size)
    ncopy >>= 1;
  float* s_ws = (float*)d_ws;
  float* vacc = s_ws + (size_t)ncopy * SVOL_;
  const size_t s_bytes = (size_t)ncopy * SVOL_ * sizeof(float);

  // pass 0: c uniform -> s0 -> v0; v_acc = v0
  hipMemsetAsync(s_ws, 0, s_bytes, stream);
  accum_kernel<0><<<NBLK_, 256, 0, stream>>>(x, W, vacc, s_ws, ncopy);
  squash_kernel<0><<<SVOL_ / 256, 256, 0, stream>>>(s_ws, ncopy, vacc, out);

  // pass 1: logits = u.v0 -> s1 -> v1; v_acc = v0 + v1
  hipMemsetAsync(s_ws, 0, s_bytes, stream);
  accum_kernel<1><<<NBLK_, 256, 0, stream>>>(x, W, vacc, s_ws, ncopy);
  squash_kernel<1><<<SVOL_ / 256, 256, 0, stream>>>(s_ws, ncopy, vacc, out);

  // pass 2: logits = u.(v0+v1) -> s2 -> v2 = output
  hipMemsetAsync(s_ws, 0, s_bytes, stream);
  accum_kernel<1><<<NBLK_, 256, 0, stream>>>(x, W, vacc, s_ws, ncopy);
  squash_kernel<2><<<SVOL_ / 256, 256, 0, stream>>>(s_ws, ncopy, vacc, out);
}

// Round 2
// 441.356 us; speedup vs baseline: 2.5585x; 2.5585x over previous
//
#include <hip/hip_runtime.h>
#include <cstdint>
#include <cstddef>

#define B_ 64
#define N_ 16384
#define C_ 10
#define D_ 8
#define E_ 16
#define BG_ 8                   // batches per block
#define NBG_ (B_ / BG_)         // 8 batch groups
#define NT_ 64                  // n's per block
#define NCH_ (NT_ / 16)         // 4 chunks of 16 n
#define NBN_ (N_ / NT_)         // 256 n-blocks
#define GRID_ (NBN_ * NBG_)     // 2048 blocks
#define SVOL_ (B_ * C_ * E_)    // 10240 floats
#define BSE_ (BG_ * C_ * E_)    // 1280 floats

// sum over the 16-lane DPP row via rotate-add (pure VALU, no DS pipe)
template <int K>
__device__ __forceinline__ float row_ror_add(float v) {
  int r = __builtin_amdgcn_update_dpp(0, __builtin_bit_cast(int, v),
                                      0x120 | K, 0xF, 0xF, false);
  return v + __builtin_bit_cast(float, r);
}
__device__ __forceinline__ float row_reduce16(float v) {
  v = row_ror_add<1>(v);
  v = row_ror_add<2>(v);
  v = row_ror_add<4>(v);
  v = row_ror_add<8>(v);
  return v;  // all 16 lanes of the row hold the row-sum
}

// ---------------------------------------------------------------------------
// One routing pass. Block = (n-slice of 64, batch-group of 8). Thread = (e, g)
// with e = capsule dim lane (16), g = n-sub within 16-n chunk.
// W slice lives in registers (80 VGPR). s partials accumulate in registers
// acc[8][10] (per-e-lane) -> shfl-reduce over g -> LDS-reduce over waves ->
// one striped global atomicAdd per element per block.
// ITER==0: uniform c = 0.1.  ITER==1: logits = u_hat . vacc (softmax, no
// max-sub needed: |logit| <= ||u||*||vacc|| ~ 10, exp safe in fp32).
// ---------------------------------------------------------------------------
template <int ITER>
__global__ __launch_bounds__(256, 2) void accum_kernel(
    const float* __restrict__ x,     // [B][N][D]
    const float* __restrict__ W,     // [N][C][D][E]
    const float* __restrict__ vacc,  // [B][C][E]
    float* __restrict__ scopy,       // [ncopy][B][C][E]
    int ncopy)
{
  __shared__ float vlds[BSE_];            // 5 KB (ITER>=1)
  __shared__ float xtile[BG_ * 16 * D_];  // 4 KB
  __shared__ float red[4 * BSE_];         // 20 KB
  const int tid = threadIdx.x;
  const int e = tid & 15;
  const int g = tid >> 4;                 // 0..15
  const int bg = blockIdx.x % NBG_;
  const int nb = blockIdx.x / NBG_;
  const int b0 = bg * BG_;
  const int n0 = nb * NT_;

  if (ITER) {
    for (int i = tid; i < BSE_; i += 256)
      vlds[i] = vacc[b0 * (C_ * E_) + i];
  }

  float acc[BG_][C_];
#pragma unroll
  for (int bi = 0; bi < BG_; ++bi)
#pragma unroll
    for (int c = 0; c < C_; ++c) acc[bi][c] = 0.f;

  for (int ch = 0; ch < NCH_; ++ch) {
    __syncthreads();  // prev chunk's xtile readers done (covers vlds on ch=0)
    // stage x[b0..b0+7][n0+ch*16 .. +15][0..7] (coalesced: 512 B rows per b)
    {
      const float* xs = x + (size_t)(n0 + ch * 16) * D_;
      for (int i = tid; i < BG_ * 128; i += 256) {
        int bi = i >> 7, r = i & 127;
        xtile[i] = xs[(size_t)(b0 + bi) * (N_ * D_) + r];
      }
    }
    // this thread's W slice -> registers
    const int n = n0 + ch * 16 + g;
    float w[C_][D_];
    const float* Wp = W + (size_t)n * (C_ * D_ * E_) + e;
#pragma unroll
    for (int c = 0; c < C_; ++c)
#pragma unroll
      for (int d = 0; d < D_; ++d) w[c][d] = Wp[(c * D_ + d) * E_];
    __syncthreads();

#pragma unroll
    for (int bi = 0; bi < BG_; ++bi) {
      float xd[D_];
#pragma unroll
      for (int d = 0; d < D_; ++d) xd[d] = xtile[bi * 128 + g * 8 + d];
      float u[C_];
#pragma unroll
      for (int c = 0; c < C_; ++c) {
        float t = xd[0] * w[c][0];
#pragma unroll
        for (int d = 1; d < D_; ++d) t = fmaf(xd[d], w[c][d], t);
        u[c] = t;
      }
      float cw[C_];
      if (ITER == 0) {
#pragma unroll
        for (int c = 0; c < C_; ++c) cw[c] = 0.1f;
      } else {
        float ssum = 0.f;
#pragma unroll
        for (int c = 0; c < C_; ++c) {
          float t = u[c] * vlds[(bi * C_ + c) * E_ + e];
          t = row_reduce16(t);        // logit a[c], all e-lanes
          cw[c] = __expf(t);
          ssum += cw[c];
        }
        float inv = __builtin_amdgcn_rcpf(ssum);
#pragma unroll
        for (int c = 0; c < C_; ++c) cw[c] *= inv;
      }
#pragma unroll
      for (int c = 0; c < C_; ++c) acc[bi][c] = fmaf(cw[c], u[c], acc[bi][c]);
    }
  }

  // reduce acc over the wave's 4 g's (lanes xor 16, 32)
#pragma unroll
  for (int bi = 0; bi < BG_; ++bi)
#pragma unroll
    for (int c = 0; c < C_; ++c) {
      float v = acc[bi][c];
      v += __shfl_xor(v, 16);
      v += __shfl_xor(v, 32);
      acc[bi][c] = v;
    }
  const int wave = tid >> 6;
  if ((tid & 63) < 16) {
#pragma unroll
    for (int bi = 0; bi < BG_; ++bi)
#pragma unroll
      for (int c = 0; c < C_; ++c)
        red[wave * BSE_ + (bi * C_ + c) * E_ + e] = acc[bi][c];
  }
  __syncthreads();
  float* sc = scopy + (size_t)(blockIdx.x & (ncopy - 1)) * SVOL_ + b0 * (C_ * E_);
  for (int i = tid; i < BSE_; i += 256) {
    float v = red[i] + red[BSE_ + i] + red[2 * BSE_ + i] + red[3 * BSE_ + i];
    atomicAdd(&sc[i], v);
  }
}

// ---------------------------------------------------------------------------
// Reduce striped s copies, apply squash. 16 consecutive lanes = one capsule.
// MODE 0: vacc = v    MODE 1: vacc += v    MODE 2: out = v
// ---------------------------------------------------------------------------
template <int MODE>
__global__ __launch_bounds__(256) void squash_kernel(
    const float* __restrict__ scopy, int ncopy,
    float* __restrict__ vacc, float* __restrict__ out)
{
  int t = blockIdx.x * 256 + threadIdx.x;  // 0..10239
  float sv = 0.f;
  for (int k = 0; k < ncopy; ++k) sv += scopy[(size_t)k * SVOL_ + t];
  float sq = row_reduce16(sv * sv);
  float scale = sq / (1.f + sq) * rsqrtf(sq + 1e-7f);
  float v = scale * sv;
  if (MODE == 0)      vacc[t] = v;
  else if (MODE == 1) vacc[t] += v;
  else                out[t] = v;
}

extern "C" void kernel_launch(void* const* d_in, const int* in_sizes, int n_in,
                              void* d_out, int out_size, void* d_ws, size_t ws_size,
                              hipStream_t stream)
{
  const float* x = (const float*)d_in[0];  // [64][16384][8]
  const float* W = (const float*)d_in[1];  // [16384][10][8][16]
  float* out = (float*)d_out;              // [64][10][16]

  int ncopy = 64;  // pow2 stripes; blockIdx%8 fixes bg so rows stay disjoint
  while (ncopy > 1 && (size_t)(ncopy + 1) * SVOL_ * sizeof(float) > ws_size)
    ncopy >>= 1;
  float* s_ws = (float*)d_ws;
  float* vacc = s_ws + (size_t)ncopy * SVOL_;
  const size_t s_bytes = (size_t)ncopy * SVOL_ * sizeof(float);

  // pass 0: uniform c -> s0 -> v0
  hipMemsetAsync(s_ws, 0, s_bytes, stream);
  accum_kernel<0><<<GRID_, 256, 0, stream>>>(x, W, vacc, s_ws, ncopy);
  squash_kernel<0><<<SVOL_ / 256, 256, 0, stream>>>(s_ws, ncopy, vacc, out);

  // pass 1: logits = u.v0 -> s1 -> v1; vacc = v0 + v1
  hipMemsetAsync(s_ws, 0, s_bytes, stream);
  accum_kernel<1><<<GRID_, 256, 0, stream>>>(x, W, vacc, s_ws, ncopy);
  squash_kernel<1><<<SVOL_ / 256, 256, 0, stream>>>(s_ws, ncopy, vacc, out);

  // pass 2: logits = u.(v0+v1) -> v2 = output
  hipMemsetAsync(s_ws, 0, s_bytes, stream);
  accum_kernel<1><<<GRID_, 256, 0, stream>>>(x, W, vacc, s_ws, ncopy);
  squash_kernel<2><<<SVOL_ / 256, 256, 0, stream>>>(s_ws, ncopy, vacc, out);
}